// Round 3
// baseline (99.452 us; speedup 1.0000x reference)
//
#include <hip/hip_runtime.h>

// EmbedAtt: out[b,d] = sum_i sigmoid((x_num[b,i]-mean[i])/(std[i]+eps)) * lin_W[i,d]
//                    + sum_i lin_b[i,d]
//                    + sum_c emb[c, x_cat[b,c], d]
// B=65536, CN=CC=16, D=128, V=65. fp32 in/out, x_cat int32.
//
// Strategy: the 512 MB gather-sum is the dominant traffic. Round-2 gathered
// from L2 (every load L1-misses; latency/miss-capacity bound). Here each block
// owns a 16-wide d-slice and stages emb[:, :, d0:d0+16] as bf16 in LDS (33 KB)
// so all 16 gathers per row are LDS-hits. lin_W slice lives in 64 VGPRs.

constexpr int CN = 16;
constexpr int CC = 16;
constexpr int D  = 128;
constexpr int V  = 65;
constexpr float EPS = 1e-5f;

constexpr int W      = 16;            // d-slice width per block
constexpr int NSLICE = D / W;         // 8
constexpr int RPB    = 512;           // rows per block
constexpr int TILE   = 64;            // rows per tile (256 thr / 4 lanes-per-row)
constexpr int NTILE  = RPB / TILE;    // 8
constexpr int PAD    = 20;            // padded row stride (ints) for z/idx tiles

__device__ __forceinline__ unsigned short f2bf(float f) {
    unsigned u = __float_as_uint(f);
    u = (u + 0x7fffu + ((u >> 16) & 1u)) >> 16;   // RNE
    return (unsigned short)u;
}

__device__ __forceinline__ void fma4(float s, const float4& w, float4& a) {
    a.x += s * w.x; a.y += s * w.y; a.z += s * w.z; a.w += s * w.w;
}

__device__ __forceinline__ void gacc(const unsigned short* p, float4& a) {
    const uint2 g = *(const uint2*)p;               // 4 bf16
    a.x += __uint_as_float(g.x << 16);
    a.y += __uint_as_float(g.x & 0xffff0000u);
    a.z += __uint_as_float(g.y << 16);
    a.w += __uint_as_float(g.y & 0xffff0000u);
}

__global__ __launch_bounds__(256, 3) void embed_att_kernel(
    const float* __restrict__ x_num,   // [B, CN]
    const float* __restrict__ means,   // [CN]
    const float* __restrict__ stds,    // [CN]
    const float* __restrict__ lin_W,   // [CN, D]
    const float* __restrict__ lin_b,   // [CN, D]
    const float* __restrict__ emb,     // [CC, V, D]
    const int*  __restrict__ x_cat,    // [B, CC]
    float* __restrict__ out)           // [B, D]
{
    __shared__ unsigned short emb_s[CC * V * W];   // 33,280 B bf16 slice
    __shared__ float z_s[2][TILE][PAD];            // 10,240 B
    __shared__ int   idx_s[2][TILE][PAD];          // 10,240 B

    const int tid = threadIdx.x;
    const int l   = tid & 3;          // lane-in-row: 4 floats of the 16-wide slice
    const int l4  = l * 4;
    const int rr  = tid >> 2;         // row-in-tile 0..63
    const int d0  = blockIdx.y * W;   // slice on y: same-chunk slices are gridDim.x
                                      // apart (128 ≡ 0 mod 8) -> same XCD, stores merge
    const int row_base = blockIdx.x * RPB;

    // ---- per-thread constants: lin_W fragment (64 VGPRs) + bias sum ----
    float4 wf[CN];
    float4 bs = make_float4(0.f, 0.f, 0.f, 0.f);
#pragma unroll
    for (int i = 0; i < CN; ++i) {
        wf[i] = *(const float4*)&lin_W[i * D + d0 + l4];
        const float4 b = *(const float4*)&lin_b[i * D + d0 + l4];
        bs.x += b.x; bs.y += b.y; bs.z += b.z; bs.w += b.w;
    }
    const float4 mm = *(const float4*)&means[l4];
    const float4 sv = *(const float4*)&stds[l4];
    const float LOG2E = 1.44269504088896340736f;
    float4 inv;
    inv.x = -LOG2E / (sv.x + EPS); inv.y = -LOG2E / (sv.y + EPS);
    inv.z = -LOG2E / (sv.z + EPS); inv.w = -LOG2E / (sv.w + EPS);

    // ---- stage emb d-slice to LDS as bf16: 1040 rows x 16 floats ----
    for (int j = tid; j < CC * V * W / 4; j += 256) {   // 4160 float4s
        const int seg = j >> 2, k = j & 3;
        const float4 e = *(const float4*)&emb[seg * D + d0 + k * 4];
        uint2 p;
        p.x = (unsigned)f2bf(e.x) | ((unsigned)f2bf(e.y) << 16);
        p.y = (unsigned)f2bf(e.z) | ((unsigned)f2bf(e.w) << 16);
        *(uint2*)&emb_s[seg * W + k * 4] = p;
    }

    // ---- prefetch tile 0's x_num/x_cat ----
    float4 xf; int4 xi;
    {
        const int row = row_base + rr;
        xf = *(const float4*)&x_num[row * CN + l4];
        xi = *(const int4*)&x_cat[row * CC + l4];
    }

    for (int t = 0; t < NTILE; ++t) {
        const int buf = t & 1;
        // write this tile's z/idx (double-buffered; one barrier per tile)
        float4 z;
        z.x = 1.f / (1.f + __builtin_amdgcn_exp2f((xf.x - mm.x) * inv.x));
        z.y = 1.f / (1.f + __builtin_amdgcn_exp2f((xf.y - mm.y) * inv.y));
        z.z = 1.f / (1.f + __builtin_amdgcn_exp2f((xf.z - mm.z) * inv.z));
        z.w = 1.f / (1.f + __builtin_amdgcn_exp2f((xf.w - mm.w) * inv.w));
        *(float4*)&z_s[buf][rr][l4] = z;
        *(int4*)&idx_s[buf][rr][l4] = xi;
        __syncthreads();   // also covers emb_s staging on t==0

        // prefetch next tile (latency hidden under this tile's compute)
        if (t + 1 < NTILE) {
            const int row = row_base + (t + 1) * TILE + rr;
            xf = *(const float4*)&x_num[row * CN + l4];
            xi = *(const int4*)&x_cat[row * CC + l4];
        }

        // gather + matmul for row (broadcast reads across the 4 lanes of a row)
        const int4 i0 = *(const int4*)&idx_s[buf][rr][0];
        const int4 i1 = *(const int4*)&idx_s[buf][rr][4];
        const int4 i2 = *(const int4*)&idx_s[buf][rr][8];
        const int4 i3 = *(const int4*)&idx_s[buf][rr][12];
        const float4 z0 = *(const float4*)&z_s[buf][rr][0];
        const float4 z1 = *(const float4*)&z_s[buf][rr][4];
        const float4 z2 = *(const float4*)&z_s[buf][rr][8];
        const float4 z3 = *(const float4*)&z_s[buf][rr][12];

        float4 acc = bs;
        fma4(z0.x, wf[0],  acc); fma4(z0.y, wf[1],  acc);
        fma4(z0.z, wf[2],  acc); fma4(z0.w, wf[3],  acc);
        fma4(z1.x, wf[4],  acc); fma4(z1.y, wf[5],  acc);
        fma4(z1.z, wf[6],  acc); fma4(z1.w, wf[7],  acc);
        fma4(z2.x, wf[8],  acc); fma4(z2.y, wf[9],  acc);
        fma4(z2.z, wf[10], acc); fma4(z2.w, wf[11], acc);
        fma4(z3.x, wf[12], acc); fma4(z3.y, wf[13], acc);
        fma4(z3.z, wf[14], acc); fma4(z3.w, wf[15], acc);

#define GAT(c, ix) gacc(&emb_s[((c) * V + (ix)) * W + l4], acc)
        GAT(0,  i0.x); GAT(1,  i0.y); GAT(2,  i0.z); GAT(3,  i0.w);
        GAT(4,  i1.x); GAT(5,  i1.y); GAT(6,  i1.z); GAT(7,  i1.w);
        GAT(8,  i2.x); GAT(9,  i2.y); GAT(10, i2.z); GAT(11, i2.w);
        GAT(12, i3.x); GAT(13, i3.y); GAT(14, i3.z); GAT(15, i3.w);
#undef GAT

        const int row = row_base + t * TILE + rr;
        *(float4*)&out[row * D + d0 + l4] = acc;
    }
}

extern "C" void kernel_launch(void* const* d_in, const int* in_sizes, int n_in,
                              void* d_out, int out_size, void* d_ws, size_t ws_size,
                              hipStream_t stream) {
    const float* x_num = (const float*)d_in[0];
    const float* means = (const float*)d_in[1];
    const float* stds  = (const float*)d_in[2];
    const float* lin_W = (const float*)d_in[3];
    const float* lin_b = (const float*)d_in[4];
    const float* emb   = (const float*)d_in[5];
    const int*   x_cat = (const int*)d_in[6];
    float* out = (float*)d_out;

    const int B      = in_sizes[0] / CN;   // 65536
    const int nchunk = B / RPB;            // 128

    dim3 grid(nchunk, NSLICE, 1);
    embed_att_kernel<<<grid, 256, 0, stream>>>(x_num, means, stds, lin_W, lin_b,
                                               emb, x_cat, out);
}